// Round 14
// baseline (337.961 us; speedup 1.0000x reference)
//
#include <hip/hip_runtime.h>
#include <hip/hip_bf16.h>

// MultiheadAttn fwd. T=2048, B=2, E=1024, H=16, hd=64.
// cast(x,Win,Wout->bf16) -> gemm_bf16<0> (MFMA QKV proj) -> flash_kernel
// (MFMA, online softmax, async reg-staged K/V, cvt_pk repack) -> avg_kernel
// (MFMA recompute, 2 q-tiles/block, async K prefetch) -> gemm_bf16<1>.

#define T_DIM 2048
#define B_DIM 2
#define E_DIM 1024
#define H_DIM 16
#define HD 64
#define F_DIM 3072
#define M_DIM (T_DIM * B_DIM)
#define SCALE 0.125f

typedef __attribute__((ext_vector_type(8))) short bf16x8;
typedef __attribute__((ext_vector_type(4))) float f32x4;

// RNE f32->bf16 via HIP intrinsic: compiler pairs these into v_cvt_pk_bf16_f32.
__device__ inline unsigned short f2bf(float f) {
    union { __hip_bfloat16 h; unsigned short u; } v;
    v.h = __float2bfloat16(f);
    return v.u;
}

// ---------------------------------------------------------------------------
// fp32 -> bf16 cast, 8 elems/thread
// ---------------------------------------------------------------------------
__global__ __launch_bounds__(256) void cast_bf16(
    const float* __restrict__ src, unsigned short* __restrict__ dst, int n8)
{
    int i = blockIdx.x * 256 + threadIdx.x;
    if (i >= n8) return;
    float4 a = *(const float4*)&src[i * 8];
    float4 b = *(const float4*)&src[i * 8 + 4];
    bf16x8 o;
    o[0] = f2bf(a.x); o[1] = f2bf(a.y); o[2] = f2bf(a.z); o[3] = f2bf(a.w);
    o[4] = f2bf(b.x); o[5] = f2bf(b.y); o[6] = f2bf(b.z); o[7] = f2bf(b.w);
    *(bf16x8*)&dst[i * 8] = o;
}

// ---------------------------------------------------------------------------
// bf16 MFMA GEMM (NT): C[r,f] = sum_e A[r,e]*W[f,e] + bias[f], K=1024.
// 128x128 tile, BK=64, 4 waves in 2x2, per-wave 64x64. (unchanged from R13)
// ---------------------------------------------------------------------------
template <int MODE>
__global__ __launch_bounds__(256) void gemm_bf16(
    const unsigned short* __restrict__ A, const unsigned short* __restrict__ W,
    const float* __restrict__ bias,
    unsigned short* __restrict__ qb, unsigned short* __restrict__ kb,
    unsigned short* __restrict__ vb, float* __restrict__ outp)
{
    __shared__ short As[128][72];
    __shared__ short Bs[128][72];

    const int tid  = threadIdx.x;
    const int lane = tid & 63;
    const int wv   = tid >> 6;
    const int l16  = lane & 15;
    const int g    = lane >> 4;
    const int wr   = wv >> 1, wc = wv & 1;
    const int n0   = blockIdx.x * 128, m0 = blockIdx.y * 128;

    const int srow = tid >> 2;
    const int sc   = (tid & 3) * 16;

    f32x4 acc[4][4] = {};

    for (int k0 = 0; k0 < E_DIM; k0 += 64) {
        __syncthreads();
#pragma unroll
        for (int i = 0; i < 2; ++i) {
            const int row = srow + i * 64;
            const size_t ga = (size_t)(m0 + row) * E_DIM + k0 + sc;
            const size_t gb = (size_t)(n0 + row) * E_DIM + k0 + sc;
            *(bf16x8*)&As[row][sc]     = *(const bf16x8*)&A[ga];
            *(bf16x8*)&As[row][sc + 8] = *(const bf16x8*)&A[ga + 8];
            *(bf16x8*)&Bs[row][sc]     = *(const bf16x8*)&W[gb];
            *(bf16x8*)&Bs[row][sc + 8] = *(const bf16x8*)&W[gb + 8];
        }
        __syncthreads();

        bf16x8 af[4][2], bf[4][2];
#pragma unroll
        for (int mt = 0; mt < 4; ++mt) {
            af[mt][0] = *(const bf16x8*)&As[wr * 64 + mt * 16 + l16][g * 8];
            af[mt][1] = *(const bf16x8*)&As[wr * 64 + mt * 16 + l16][32 + g * 8];
        }
#pragma unroll
        for (int nt = 0; nt < 4; ++nt) {
            bf[nt][0] = *(const bf16x8*)&Bs[wc * 64 + nt * 16 + l16][g * 8];
            bf[nt][1] = *(const bf16x8*)&Bs[wc * 64 + nt * 16 + l16][32 + g * 8];
        }
#pragma unroll
        for (int mt = 0; mt < 4; ++mt)
#pragma unroll
            for (int nt = 0; nt < 4; ++nt) {
                acc[mt][nt] = __builtin_amdgcn_mfma_f32_16x16x32_bf16(
                    af[mt][0], bf[nt][0], acc[mt][nt], 0, 0, 0);
                acc[mt][nt] = __builtin_amdgcn_mfma_f32_16x16x32_bf16(
                    af[mt][1], bf[nt][1], acc[mt][nt], 0, 0, 0);
            }
    }

#pragma unroll
    for (int mt = 0; mt < 4; ++mt)
#pragma unroll
        for (int nt = 0; nt < 4; ++nt)
#pragma unroll
            for (int rr = 0; rr < 4; ++rr) {
                const int r = m0 + wr * 64 + mt * 16 + g * 4 + rr;
                const int f = n0 + wc * 64 + nt * 16 + l16;
                float val = acc[mt][nt][rr] + bias[f];
                if (MODE == 0) {
                    const int t = r >> 1, b = r & 1;
                    const int sec = f >> 10, rem = f & 1023;
                    const int h = rem >> 6, d = rem & 63;
                    const size_t idx = ((size_t)(b * H_DIM + h) * T_DIM + t) * HD + d;
                    if (sec == 0)      qb[idx] = f2bf(val * SCALE);
                    else if (sec == 1) kb[idx] = f2bf(val);
                    else               vb[idx] = f2bf(val);
                } else {
                    outp[(size_t)r * E_DIM + f] = val;
                }
            }
}

// ---------------------------------------------------------------------------
// Flash attention. Block = (q-tile 64, head n), 4 waves.
// Async reg-staged K/V: loads for tile t+1 issued before compute on tile t.
// ---------------------------------------------------------------------------
__global__ __launch_bounds__(256) void flash_kernel(
    const unsigned short* __restrict__ qb, const unsigned short* __restrict__ kb,
    const unsigned short* __restrict__ vb, unsigned short* __restrict__ ctxbuf,
    float2* __restrict__ ml)
{
    __shared__ short Ks[64][72];
    __shared__ short Vt[64][72];
    __shared__ short Ps[64][72];

    const int tid  = threadIdx.x;
    const int lane = tid & 63;
    const int w    = tid >> 6;
    const int l16  = lane & 15;
    const int g    = lane >> 4;
    const int q0   = blockIdx.x * 64;
    const int n    = blockIdx.y;
    const int b    = n >> 4, h = n & 15;

    const int krow = tid >> 2, kd0 = (tid & 3) << 4;
    const int vrow = tid & 63, vd0 = (tid >> 6) << 4;

    const size_t qrow = (size_t)n * T_DIM + q0 + w * 16 + l16;
    bf16x8 qf0 = *(const bf16x8*)&qb[qrow * HD + g * 8];
    bf16x8 qf1 = *(const bf16x8*)&qb[qrow * HD + 32 + g * 8];

    f32x4 ctx[4] = {};
    float m_[4], l_[4];
#pragma unroll
    for (int r = 0; r < 4; ++r) { m_[r] = -1e30f; l_[r] = 0.f; }

    // preload tile 0 into registers
    const size_t hbase = (size_t)n * T_DIM;
    bf16x8 kreg0 = *(const bf16x8*)&kb[(hbase + krow) * HD + kd0];
    bf16x8 kreg1 = *(const bf16x8*)&kb[(hbase + krow) * HD + kd0 + 8];
    bf16x8 vreg0 = *(const bf16x8*)&vb[(hbase + vrow) * HD + vd0];
    bf16x8 vreg1 = *(const bf16x8*)&vb[(hbase + vrow) * HD + vd0 + 8];

    for (int kt = 0; kt < T_DIM; kt += 64) {
        __syncthreads();                      // prev readers done
        // commit staged regs to LDS
        *(bf16x8*)&Ks[krow][kd0]     = kreg0;
        *(bf16x8*)&Ks[krow][kd0 + 8] = kreg1;
#pragma unroll
        for (int e = 0; e < 8; ++e) {
            Vt[vd0 + e][vrow]     = vreg0[e];
            Vt[vd0 + 8 + e][vrow] = vreg1[e];
        }
        // issue next tile's loads (land during compute below)
        if (kt + 64 < T_DIM) {
            const size_t kg = hbase + kt + 64;
            kreg0 = *(const bf16x8*)&kb[(kg + krow) * HD + kd0];
            kreg1 = *(const bf16x8*)&kb[(kg + krow) * HD + kd0 + 8];
            vreg0 = *(const bf16x8*)&vb[(kg + vrow) * HD + vd0];
            vreg1 = *(const bf16x8*)&vb[(kg + vrow) * HD + vd0 + 8];
        }
        __syncthreads();                      // LDS tile ready

        f32x4 s[4];
#pragma unroll
        for (int nt = 0; nt < 4; ++nt) {
            bf16x8 kf0 = *(const bf16x8*)&Ks[nt * 16 + l16][g * 8];
            bf16x8 kf1 = *(const bf16x8*)&Ks[nt * 16 + l16][32 + g * 8];
            f32x4 z = {0.f, 0.f, 0.f, 0.f};
            z = __builtin_amdgcn_mfma_f32_16x16x32_bf16(qf0, kf0, z, 0, 0, 0);
            z = __builtin_amdgcn_mfma_f32_16x16x32_bf16(qf1, kf1, z, 0, 0, 0);
            s[nt] = z;
        }

        float p[4][4];
#pragma unroll
        for (int r = 0; r < 4; ++r) {
            float mt = fmaxf(fmaxf(s[0][r], s[1][r]), fmaxf(s[2][r], s[3][r]));
            mt = fmaxf(mt, __shfl_xor(mt, 1));
            mt = fmaxf(mt, __shfl_xor(mt, 2));
            mt = fmaxf(mt, __shfl_xor(mt, 4));
            mt = fmaxf(mt, __shfl_xor(mt, 8));
            float mnew = fmaxf(m_[r], mt);
            float f = __expf(m_[r] - mnew);
            float rs = 0.f;
#pragma unroll
            for (int nt = 0; nt < 4; ++nt) { p[nt][r] = __expf(s[nt][r] - mnew); rs += p[nt][r]; }
            rs += __shfl_xor(rs, 1);
            rs += __shfl_xor(rs, 2);
            rs += __shfl_xor(rs, 4);
            rs += __shfl_xor(rs, 8);
            l_[r] = l_[r] * f + rs;
            m_[r] = mnew;
#pragma unroll
            for (int dt = 0; dt < 4; ++dt) ctx[dt][r] *= f;
        }

#pragma unroll
        for (int nt = 0; nt < 4; ++nt)
#pragma unroll
            for (int r = 0; r < 4; ++r)
                Ps[w * 16 + g * 4 + r][nt * 16 + l16] = (short)f2bf(p[nt][r]);

        bf16x8 pa0 = *(const bf16x8*)&Ps[w * 16 + l16][g * 8];
        bf16x8 pa1 = *(const bf16x8*)&Ps[w * 16 + l16][32 + g * 8];
#pragma unroll
        for (int dt = 0; dt < 4; ++dt) {
            bf16x8 vf0 = *(const bf16x8*)&Vt[dt * 16 + l16][g * 8];
            bf16x8 vf1 = *(const bf16x8*)&Vt[dt * 16 + l16][32 + g * 8];
            ctx[dt] = __builtin_amdgcn_mfma_f32_16x16x32_bf16(pa0, vf0, ctx[dt], 0, 0, 0);
            ctx[dt] = __builtin_amdgcn_mfma_f32_16x16x32_bf16(pa1, vf1, ctx[dt], 0, 0, 0);
        }
    }

    float linv[4];
#pragma unroll
    for (int r = 0; r < 4; ++r) linv[r] = 1.0f / l_[r];

#pragma unroll
    for (int dt = 0; dt < 4; ++dt)
#pragma unroll
        for (int r = 0; r < 4; ++r) {
            const int q = q0 + w * 16 + g * 4 + r;
            const int d = dt * 16 + l16;
            ctxbuf[((size_t)q * B_DIM + b) * E_DIM + h * HD + d] = f2bf(ctx[dt][r] * linv[r]);
        }

    if (l16 == 0) {
#pragma unroll
        for (int r = 0; r < 4; ++r)
            ml[(size_t)n * T_DIM + q0 + w * 16 + g * 4 + r] = make_float2(m_[r], linv[r]);
    }
}

// ---------------------------------------------------------------------------
// avg_weights: block = (kt-tile 64, q-tile 128, b). 2 q-tiles share each
// staged K tile; async K prefetch across the h loop. No atomics.
// ---------------------------------------------------------------------------
__global__ __launch_bounds__(256) void avg_kernel(
    const unsigned short* __restrict__ qb, const unsigned short* __restrict__ kb,
    const float2* __restrict__ ml, float* __restrict__ avg)
{
    __shared__ short Kh[64][72];

    const int tid  = threadIdx.x;
    const int lane = tid & 63;
    const int w    = tid >> 6;
    const int l16  = lane & 15;
    const int g    = lane >> 4;
    const int kt0  = blockIdx.x * 64;
    const int q0   = blockIdx.y * 128;
    const int b    = blockIdx.z;

    const int krow = tid >> 2, kd0 = (tid & 3) << 4;

    f32x4 acc[2][4] = {};   // [qtile][ntile]

    // preload h=0 K tile
    bf16x8 kreg0 = *(const bf16x8*)&kb[((size_t)(b * H_DIM) * T_DIM + kt0 + krow) * HD + kd0];
    bf16x8 kreg1 = *(const bf16x8*)&kb[((size_t)(b * H_DIM) * T_DIM + kt0 + krow) * HD + kd0 + 8];

    for (int h = 0; h < H_DIM; ++h) {
        const int n = b * H_DIM + h;
        __syncthreads();
        *(bf16x8*)&Kh[krow][kd0]     = kreg0;
        *(bf16x8*)&Kh[krow][kd0 + 8] = kreg1;
        if (h + 1 < H_DIM) {
            const size_t kg = (size_t)(n + 1) * T_DIM + kt0 + krow;
            kreg0 = *(const bf16x8*)&kb[kg * HD + kd0];
            kreg1 = *(const bf16x8*)&kb[kg * HD + kd0 + 8];
        }
        __syncthreads();

#pragma unroll
        for (int qt = 0; qt < 2; ++qt) {
            const size_t qrow = (size_t)n * T_DIM + q0 + qt * 64 + w * 16 + l16;
            bf16x8 qf0 = *(const bf16x8*)&qb[qrow * HD + g * 8];
            bf16x8 qf1 = *(const bf16x8*)&qb[qrow * HD + 32 + g * 8];

            float2 mlv[4];
#pragma unroll
            for (int r = 0; r < 4; ++r)
                mlv[r] = ml[(size_t)n * T_DIM + q0 + qt * 64 + w * 16 + g * 4 + r];

#pragma unroll
            for (int nt = 0; nt < 4; ++nt) {
                bf16x8 kf0 = *(const bf16x8*)&Kh[nt * 16 + l16][g * 8];
                bf16x8 kf1 = *(const bf16x8*)&Kh[nt * 16 + l16][32 + g * 8];
                f32x4 z = {0.f, 0.f, 0.f, 0.f};
                z = __builtin_amdgcn_mfma_f32_16x16x32_bf16(qf0, kf0, z, 0, 0, 0);
                z = __builtin_amdgcn_mfma_f32_16x16x32_bf16(qf1, kf1, z, 0, 0, 0);
#pragma unroll
                for (int r = 0; r < 4; ++r)
                    acc[qt][nt][r] += __expf(z[r] - mlv[r].x) * mlv[r].y * (1.0f / H_DIM);
            }
        }
    }

#pragma unroll
    for (int qt = 0; qt < 2; ++qt)
#pragma unroll
        for (int nt = 0; nt < 4; ++nt)
#pragma unroll
            for (int r = 0; r < 4; ++r) {
                const int q = q0 + qt * 64 + w * 16 + g * 4 + r;
                avg[((size_t)b * T_DIM + q) * T_DIM + kt0 + nt * 16 + l16] = acc[qt][nt][r];
            }
}

// ---------------------------------------------------------------------------
extern "C" void kernel_launch(void* const* d_in, const int* in_sizes, int n_in,
                              void* d_out, int out_size, void* d_ws, size_t ws_size,
                              hipStream_t stream)
{
    const float* x     = (const float*)d_in[0];
    const float* w_in  = (const float*)d_in[1];
    const float* b_in  = (const float*)d_in[2];
    const float* w_out = (const float*)d_in[3];
    const float* b_out = (const float*)d_in[4];

    float* out = (float*)d_out;
    float* avg = out + (size_t)T_DIM * B_DIM * E_DIM;

    const size_t HSZ = (size_t)B_DIM * H_DIM * T_DIM * HD;     // 4M elems
    unsigned short* qb   = (unsigned short*)d_ws;
    unsigned short* kb   = qb + HSZ;
    unsigned short* vb   = kb + HSZ;
    unsigned short* ctxb = vb + HSZ;                            // [T,B,E] bf16
    unsigned short* xb   = ctxb + (size_t)T_DIM * B_DIM * E_DIM;
    unsigned short* wbin = xb + (size_t)T_DIM * B_DIM * E_DIM;  // [3E,E]
    unsigned short* wbot = wbin + (size_t)F_DIM * E_DIM;        // [E,E]
    float2* ml = (float2*)(wbot + (size_t)E_DIM * E_DIM);

    // 0. casts
    cast_bf16<<<(T_DIM * B_DIM * E_DIM / 8 + 255) / 256, 256, 0, stream>>>(
        x, xb, T_DIM * B_DIM * E_DIM / 8);
    cast_bf16<<<(F_DIM * E_DIM / 8 + 255) / 256, 256, 0, stream>>>(
        w_in, wbin, F_DIM * E_DIM / 8);
    cast_bf16<<<(E_DIM * E_DIM / 8 + 255) / 256, 256, 0, stream>>>(
        w_out, wbot, E_DIM * E_DIM / 8);

    // 1. QKV projection (MFMA bf16)
    gemm_bf16<0><<<dim3(F_DIM / 128, M_DIM / 128), 256, 0, stream>>>(
        xb, wbin, b_in, qb, kb, vb, nullptr);

    // 2. flash attention
    flash_kernel<<<dim3(T_DIM / 64, B_DIM * H_DIM), 256, 0, stream>>>(
        qb, kb, vb, ctxb, ml);

    // 3. avg weights (2 q-tiles per block)
    avg_kernel<<<dim3(T_DIM / 64, T_DIM / 128, B_DIM), 256, 0, stream>>>(
        qb, kb, ml, avg);

    // 4. output projection (MFMA bf16 -> fp32)
    gemm_bf16<1><<<dim3(E_DIM / 128, M_DIM / 128), 256, 0, stream>>>(
        ctxb, wbot, b_out, nullptr, nullptr, nullptr, out);
}